// Round 21
// baseline (254.140 us; speedup 1.0000x reference)
//
#include <hip/hip_runtime.h>
#include <cstdint>

// ---------------------------------------------------------------------------
// NEO vision embeddings, MI355X (gfx950) — round 21: patch -> 128x256 tile,
// 4 waves / 256 thr, BK=32, 48KB dbuf LDS => 2 blocks/CU (two independent
// barrier domains per CU). Write-late staging (r20), vectorized epilogue.
// dense r9 exact; conv r20 exact.
//   GEMM1: peM = merge(rope(gelu(pix @ B1^T + b1)))  (128x256, BK=32, dbuf)
//   GEMM2: out = peM[8192,4096] @ B2^T + b2          (256^2 BK=64, r9)
// LDS slot (24KB): A [128 rows][32 f16] | B [256 rows][32 f16]; 64-B rows,
// 4 chunks/row, slot = c ^ (row&3) ^ ((row>>2)&3)  (<=2-way, free).
// ---------------------------------------------------------------------------

using f16x8 = __attribute__((ext_vector_type(8))) _Float16;
using f16x4 = __attribute__((ext_vector_type(4))) _Float16;
using f32x4 = __attribute__((ext_vector_type(4))) float;

__device__ __forceinline__ void gload_lds16(const void* g, void* l) {
  __builtin_amdgcn_global_load_lds(
      reinterpret_cast<const __attribute__((address_space(1))) unsigned int*>(
          reinterpret_cast<uintptr_t>(g)),
      reinterpret_cast<__attribute__((address_space(3))) unsigned int*>(
          reinterpret_cast<uintptr_t>(l)),
      16, 0, 0);
}

#define BAR   asm volatile("s_barrier" ::: "memory")
#define LGKM0 asm volatile("s_waitcnt lgkmcnt(0)" ::: "memory")
#define VM0   asm volatile("s_waitcnt vmcnt(0)" ::: "memory")

#define KP 640   // padded K stride for b1 (zeros for k >= 588)

// -------------------------- weight conversion ------------------------------

__global__ void conv_w_kernel(const float* __restrict__ w1,
                              const float* __restrict__ w2,
                              _Float16* __restrict__ h1,
                              _Float16* __restrict__ h2) {
  const int bid = blockIdx.x;
  if (bid < 2560) {                                // b1: 1024*640
    int i = bid * 256 + threadIdx.x;
    int e = i / KP;
    int k = i - e * KP;
    float v = (k < 588) ? w1[(size_t)e * 588 + k] : 0.0f;
    h1[i] = (_Float16)v;
  } else {                                         // b2: 2048*1024 float4s
    int j = (bid - 2560) * 256 + threadIdx.x;
    int o = j >> 10;
    int e = j & 1023;
    const float4 v = *(const float4*)(w2 + (size_t)o * 4096 + e * 4);
    h2[(size_t)o * 4096 + e]        = (_Float16)v.x;
    h2[(size_t)o * 4096 + 1024 + e] = (_Float16)v.y;
    h2[(size_t)o * 4096 + 2048 + e] = (_Float16)v.z;
    h2[(size_t)o * 4096 + 3072 + e] = (_Float16)v.w;
  }
}

// ------------------------- dense GEMM body macros (r9) ---------------------

#define MFMA16(I0, J0, AV, BV)                                                \
  _Pragma("unroll") for (int i_ = 0; i_ < 4; ++i_)                            \
  _Pragma("unroll") for (int j_ = 0; j_ < 2; ++j_)                            \
  _Pragma("unroll") for (int k_ = 0; k_ < 2; ++k_)                            \
      acc[(I0) + i_][(J0) + j_] = __builtin_amdgcn_mfma_f32_16x16x32_f16(     \
          AV[i_][k_], BV[j_][k_], acc[(I0) + i_][(J0) + j_], 0, 0, 0);

#define TILE_BODY(sb)                                                         \
  {                                                                           \
    f16x8 a0[4][2], a1[4][2], vb0[2][2], vb1[2][2];                           \
    _Pragma("unroll") for (int i = 0; i < 4; ++i) {                           \
      a0[i][0] = *(const f16x8*)(lbase + (sb) + aoff + i * 2048 + so0);       \
      a0[i][1] = *(const f16x8*)(lbase + (sb) + aoff + i * 2048 + so1);       \
    }                                                                         \
    _Pragma("unroll") for (int j = 0; j < 2; ++j) {                           \
      vb0[j][0] = *(const f16x8*)(lbase + (sb) + boff + j * 2048 + so0);      \
      vb0[j][1] = *(const f16x8*)(lbase + (sb) + boff + j * 2048 + so1);      \
    }                                                                         \
    MFMA16(0, 0, a0, vb0);                                                    \
    _Pragma("unroll") for (int j = 0; j < 2; ++j) {                           \
      vb1[j][0] = *(const f16x8*)(lbase + (sb) + boff + (2+j) * 2048 + so0);  \
      vb1[j][1] = *(const f16x8*)(lbase + (sb) + boff + (2+j) * 2048 + so1);  \
    }                                                                         \
    MFMA16(0, 2, a0, vb1);                                                    \
    _Pragma("unroll") for (int i = 0; i < 4; ++i) {                           \
      a1[i][0] = *(const f16x8*)(lbase + (sb) + aoff + (4+i) * 2048 + so0);   \
      a1[i][1] = *(const f16x8*)(lbase + (sb) + aoff + (4+i) * 2048 + so1);   \
    }                                                                         \
    MFMA16(4, 2, a1, vb1);                                                    \
    MFMA16(4, 0, a1, vb0);                                                    \
  }

// ---------- GEMM1: 128x256, 4 waves, BK=32, 48KB dbuf, 2 blocks/CU ---------

__global__ __launch_bounds__(256, 2) void patch_gemm21(
    const float* __restrict__ pix,
    const _Float16* __restrict__ b1w,
    const float* __restrict__ bias1,
    const float* __restrict__ cosx, const float* __restrict__ sinx,
    const float* __restrict__ cosy, const float* __restrict__ siny,
    _Float16* __restrict__ peM)
{
  __shared__ char lds[49152];   // [slot 24KB x2]: A 8KB | B 16KB

  const int tid  = threadIdx.x;
  const int lane = tid & 63;
  const int wave = tid >> 6;            // 0..3
  const int wm = wave >> 1, wn = wave & 1;
  const int bm = blockIdx.x, bn = blockIdx.y;
  const int l15 = lane & 15;
  const int g   = lane >> 4;

  const int bm128 = bm * 128, bn256 = bn * 256;

  // fragment-read geometry (xr lane-only: row&3=l15&3, (row>>2)&3=(l15>>2)&3)
  const unsigned xr  = (unsigned)((l15 & 3) ^ ((l15 >> 2) & 3));
  const unsigned soX = ((unsigned)g ^ xr) * 16u;
  const unsigned aoff = (unsigned)(wm * 4096 + l15 * 64);
  const unsigned boff = (unsigned)(8192 + wn * 8192 + l15 * 64);

  // A staging: thread -> (row, half); 4 float4 of f32, 2 swizzled chunks
  const int arow = tid >> 1, ah = tid & 1;
  const int axr  = (arow & 3) ^ ((arow >> 2) & 3);
  // B staging: wave instr u covers rows 16*(wave*4+u); lane-only gcol
  const int bgc  = (lane & 3) ^ ((lane >> 2) & 3) ^ ((lane >> 4) & 3);

  auto LOADA = [&](int s, float4 (&ar)[4]) {
    const bool full = (s < 18);
#pragma unroll
    for (int q = 0; q < 4; ++q) {
      const int col = s * 32 + ah * 16 + q * 4;
      if (full || col + 4 <= 588)
        ar[q] = *(const float4*)(pix + (size_t)(bm128 + arow) * 588 + col);
      else
        ar[q] = make_float4(0.f, 0.f, 0.f, 0.f);
    }
  };
  auto WRITEA = [&](int s, float4 (&ar)[4]) {
    char* slot = lds + (s & 1) * 24576;
#pragma unroll
    for (int cp = 0; cp < 2; ++cp) {
      f16x8 v;
      v[0] = (_Float16)ar[2*cp].x; v[1] = (_Float16)ar[2*cp].y;
      v[2] = (_Float16)ar[2*cp].z; v[3] = (_Float16)ar[2*cp].w;
      v[4] = (_Float16)ar[2*cp+1].x; v[5] = (_Float16)ar[2*cp+1].y;
      v[6] = (_Float16)ar[2*cp+1].z; v[7] = (_Float16)ar[2*cp+1].w;
      const int c = 2 * ah + cp;
      *(f16x8*)(slot + arow * 64 + ((c ^ axr) * 16)) = v;
    }
  };
  auto STAGE_B = [&](int s) {
    char* slot = lds + (s & 1) * 24576;
#pragma unroll
    for (int u = 0; u < 4; ++u) {
      const int b16 = wave * 4 + u;           // 16-row group 0..15
      const int row = b16 * 16 + (lane >> 2);
      gload_lds16(b1w + (size_t)(bn256 + row) * KP + s * 32 + bgc * 8,
                  slot + 8192 + b16 * 1024);
    }
  };

  f32x4 acc[4][8] = {};
  float4 areg[4];

  LOADA(0, areg); STAGE_B(0);
  VM0; WRITEA(0, areg); LGKM0; BAR;

  for (int s = 0; s < 19; ++s) {
    const int sb = (s & 1) * 24576;
    const bool st = (s + 1 < 19);
    if (st) { LOADA(s + 1, areg); STAGE_B(s + 1); }   // issue early
    __builtin_amdgcn_s_setprio(1);
    f16x8 a[4], b[8];
#pragma unroll
    for (int i = 0; i < 4; ++i)
      a[i] = *(const f16x8*)(lds + sb + aoff + i * 1024 + soX);
#pragma unroll
    for (int j = 0; j < 8; ++j)
      b[j] = *(const f16x8*)(lds + sb + boff + j * 1024 + soX);
#pragma unroll
    for (int i = 0; i < 4; ++i)
#pragma unroll
      for (int j = 0; j < 8; ++j)
        acc[i][j] = __builtin_amdgcn_mfma_f32_16x16x32_f16(
            a[i], b[j], acc[i][j], 0, 0, 0);
    __builtin_amdgcn_s_setprio(0);
    if (st) { VM0; WRITEA(s + 1, areg); }             // write late
    LGKM0; BAR;
  }

  // ---- epilogue: per-wave transpose (16 x 129 f32 = 8.3KB/wave) -----------
  float* sw = (float*)(lds) + wave * (16 * 129);
  const int md = (lane >> 4) * 4;
  const int rq = lane & 3;          // 32-e quarter of the wave's 128 cols
  const int lr = lane >> 2;         // row 0..15
#pragma unroll
  for (int p = 0; p < 4; ++p) {
    // scatter acc[p][*][*] (16 rows x 128 cols)
#pragma unroll
    for (int r = 0; r < 4; ++r) {
      const int lrow = md + r;
#pragma unroll
      for (int nf = 0; nf < 8; ++nf)
        sw[lrow * 129 + nf * 16 + l15] = acc[p][nf][r];
    }
    // gather: thread owns 32 consecutive cols of row lr
    {
      const int m   = bm128 + wm * 64 + p * 16 + lr;
      const int pid = m & 4095;
      const int yy = pid >> 6, xx = pid & 63;
      const int t  = (m >> 12) * 1024 + (yy >> 1) * 32 + (xx >> 1);
      const int pq = (yy & 1) * 2 + (xx & 1);
      const int e0 = bn256 + wn * 128 + rq * 32;
      const int h2 = (e0 >= 512) ? 1 : 0;
      const int idx0 = (h2 ? (e0 - 512) : e0) >> 1;    // 16 pairs
      const int pos  = h2 ? yy : xx;
      const float* ct = (h2 ? cosy : cosx) + pos * 256 + idx0;
      const float* st = (h2 ? siny : sinx) + pos * 256 + idx0;
      float cc[16], ss[16], bb[32];
#pragma unroll
      for (int q = 0; q < 4; ++q) {
        *(float4*)&cc[q * 4] = *(const float4*)(ct + q * 4);
        *(float4*)&ss[q * 4] = *(const float4*)(st + q * 4);
      }
#pragma unroll
      for (int q = 0; q < 8; ++q)
        *(float4*)&bb[q * 4] = *(const float4*)(bias1 + e0 + q * 4);
      float v[32];
#pragma unroll
      for (int j = 0; j < 32; ++j) {
        float x = sw[lr * 129 + rq * 32 + j] + bb[j];
        v[j] = 0.5f * x * (1.0f + erff(x * 0.70710678118654752f));
      }
      _Float16 o[32];
#pragma unroll
      for (int k = 0; k < 16; ++k) {
        o[2*k]   = (_Float16)(v[2*k] * cc[k] - v[2*k+1] * ss[k]);
        o[2*k+1] = (_Float16)(v[2*k] * ss[k] + v[2*k+1] * cc[k]);
      }
      _Float16* dst = peM + (size_t)t * 4096 + pq * 1024 + e0;
#pragma unroll
      for (int q = 0; q < 4; ++q)
        *(f16x8*)(dst + q * 8) = *(const f16x8*)&o[q * 8];
    }
  }
}

// ------------------- GEMM2: r9 exact (127.5 us, MfmaUtil 50%) --------------

__global__ __launch_bounds__(512, 2) void dense_gemm9(
    const _Float16* __restrict__ aM,    // [8192][4096] merged pe
    const _Float16* __restrict__ bM,    // [2048][4096] permuted w2
    const float* __restrict__ bias2, float* __restrict__ out)
{
  __shared__ _Float16 lds[2][2][256][64];   // 128 KiB

  const int tid  = threadIdx.x;
  const int lane = tid & 63;
  const int wave = tid >> 6;
  const int wm = wave >> 2, wn = wave & 3;
  const int bm = blockIdx.x, bn = blockIdx.y;
  const int l15 = lane & 15;
  const int g   = lane >> 4;
  const int s7  = l15 & 7;

  const char* lbase = (const char*)lds;
  char*       lw    = (char*)lds;
  const unsigned aoff = (unsigned)(wm * 16384 + l15 * 128);
  const unsigned boff = (unsigned)(32768 + wn * 8192 + l15 * 128);
  const unsigned so0  = (unsigned)(((0 + g) ^ s7) * 16);
  const unsigned so1  = (unsigned)(((4 + g) ^ s7) * 16);

  const int bm256 = bm * 256, bn256 = bn * 256;
  const int srow = (wave * 4) * 8 + (lane >> 3);

  auto STAGE = [&](int s) {
    char* slot = lw + ((size_t)(s & 1) << 16);
    const int c0 = s * 64;
#pragma unroll
    for (int u = 0; u < 4; ++u) {
      const int row  = srow + u * 8;
      const int gcol = (lane & 7) ^ (row & 7);
      gload_lds16(aM + (size_t)(bm256 + row) * 4096 + c0 + gcol * 8,
                  slot + (wave * 4 + u) * 1024);
      gload_lds16(bM + (size_t)(bn256 + row) * 4096 + c0 + gcol * 8,
                  slot + 32768 + (wave * 4 + u) * 1024);
    }
  };

  f32x4 acc[8][4] = {};

  STAGE(0); VM0; BAR;
#pragma unroll 2
  for (int s = 0; s < 64; ++s) {
    if (s + 1 < 64) STAGE(s + 1);
    const unsigned sb = (unsigned)((s & 1) << 16);
    __builtin_amdgcn_s_setprio(1);
    TILE_BODY(sb);
    __builtin_amdgcn_s_setprio(0);
    LGKM0; VM0; BAR;
  }

  // epilogue
  const int md = (lane >> 4) * 4;
  const int r0 = bm256 + wm * 128;
  const int c0 = bn256 + wn * 64;
#pragma unroll
  for (int nf = 0; nf < 4; ++nf) {
    const int o = c0 + nf * 16 + l15;
    const float bs = bias2[o];
#pragma unroll
    for (int mf = 0; mf < 8; ++mf) {
      const int t_ = r0 + mf * 16 + md;
#pragma unroll
      for (int r = 0; r < 4; ++r)
        out[(size_t)(t_ + r) * 2048 + o] = acc[mf][nf][r] + bs;
    }
  }
}

// ----------------------------- launcher ------------------------------------

extern "C" void kernel_launch(void* const* d_in, const int* in_sizes, int n_in,
                              void* d_out, int out_size, void* d_ws, size_t ws_size,
                              hipStream_t stream) {
  const float* pix  = (const float*)d_in[0];
  const float* w1   = (const float*)d_in[2];
  const float* b1   = (const float*)d_in[3];
  const float* w2   = (const float*)d_in[4];
  const float* b2   = (const float*)d_in[5];
  const float* cosx = (const float*)d_in[6];
  const float* sinx = (const float*)d_in[7];
  const float* cosy = (const float*)d_in[8];
  const float* siny = (const float*)d_in[9];
  float* out = (float*)d_out;

  _Float16* ws = (_Float16*)d_ws;
  const size_t PE_N  = (size_t)8192 * 4096;
  const size_t B1_N  = (size_t)1024 * KP;
  _Float16* peM  = ws;
  _Float16* b1h  = peM + PE_N;
  _Float16* b2h  = b1h + B1_N;
  // total ws ~84 MB

  conv_w_kernel<<<dim3(2560 + 8192), dim3(256), 0, stream>>>(w1, w2, b1h, b2h);
  patch_gemm21<<<dim3(256, 4), dim3(256), 0, stream>>>(
      pix, b1h, b1, cosx, sinx, cosy, siny, peM);
  dense_gemm9<<<dim3(32, 8), dim3(512), 0, stream>>>(
      peM, b2h, b2, out);
}

// Round 22
// 245.522 us; speedup vs baseline: 1.0351x; 1.0351x over previous
//
#include <hip/hip_runtime.h>
#include <cstdint>

// ---------------------------------------------------------------------------
// NEOVisionEmbeddings, MI355X (gfx950) — FINAL (r20 composition, 246.0 us):
//   conv_w:  B1 f16 [1024][640] (zero-pad), B2 f16 k-permuted [2048][4096]
//   GEMM1 (patch): peM = merge(rope(gelu(pix @ B1^T + b1)))
//     256^2 tile, BK=64, 8 waves, dbuf 128KB LDS, fused f32->f16 reg-staged A
//     (no pixel pre-pass), gload_lds B, write-late staging (T14), one
//     barrier/iter, XOR-swizzled (c ^ row&7) conflict-free LDS, vectorized
//     LDS-transposed epilogue (f16x8 stores, float4 table loads, in-thread
//     RoPE pairs), PE written pre-merged [8192][4096] for GEMM2.
//   GEMM2 (dense): out = peM @ B2^T + b2
//     256^2 tile, BK=64, 8 waves, dbuf, both operands via global_load_lds
//     (8x128B coalesced rows/instr), 64 MFMA between barriers, setprio(1).
// ---------------------------------------------------------------------------

using f16x8 = __attribute__((ext_vector_type(8))) _Float16;
using f16x4 = __attribute__((ext_vector_type(4))) _Float16;
using f32x4 = __attribute__((ext_vector_type(4))) float;

__device__ __forceinline__ void gload_lds16(const void* g, void* l) {
  __builtin_amdgcn_global_load_lds(
      reinterpret_cast<const __attribute__((address_space(1))) unsigned int*>(
          reinterpret_cast<uintptr_t>(g)),
      reinterpret_cast<__attribute__((address_space(3))) unsigned int*>(
          reinterpret_cast<uintptr_t>(l)),
      16, 0, 0);
}

#define BAR   asm volatile("s_barrier" ::: "memory")
#define LGKM0 asm volatile("s_waitcnt lgkmcnt(0)" ::: "memory")
#define VM0   asm volatile("s_waitcnt vmcnt(0)" ::: "memory")

#define KP 640   // padded K for GEMM1 (588 -> 640 = 10 x 64)

// -------------------------- weight conversion ------------------------------

__global__ void conv_w_kernel(const float* __restrict__ w1,
                              const float* __restrict__ w2,
                              _Float16* __restrict__ h1,
                              _Float16* __restrict__ h2) {
  const int bid = blockIdx.x;
  if (bid < 2560) {                                // b1: 1024*640
    int i = bid * 256 + threadIdx.x;
    int e = i / KP;
    int k = i - e * KP;
    float v = (k < 588) ? w1[(size_t)e * 588 + k] : 0.0f;
    h1[i] = (_Float16)v;
  } else {                                         // b2: 2048*1024 float4s
    int j = (bid - 2560) * 256 + threadIdx.x;
    int o = j >> 10;
    int e = j & 1023;
    const float4 v = *(const float4*)(w2 + (size_t)o * 4096 + e * 4);
    h2[(size_t)o * 4096 + e]        = (_Float16)v.x;
    h2[(size_t)o * 4096 + 1024 + e] = (_Float16)v.y;
    h2[(size_t)o * 4096 + 2048 + e] = (_Float16)v.z;
    h2[(size_t)o * 4096 + 3072 + e] = (_Float16)v.w;
  }
}

// ------------------------- shared GEMM body macros -------------------------

#define MFMA16(I0, J0, AV, BV)                                                \
  _Pragma("unroll") for (int i_ = 0; i_ < 4; ++i_)                            \
  _Pragma("unroll") for (int j_ = 0; j_ < 2; ++j_)                            \
  _Pragma("unroll") for (int k_ = 0; k_ < 2; ++k_)                            \
      acc[(I0) + i_][(J0) + j_] = __builtin_amdgcn_mfma_f32_16x16x32_f16(     \
          AV[i_][k_], BV[j_][k_], acc[(I0) + i_][(J0) + j_], 0, 0, 0);

#define TILE_BODY(sb)                                                         \
  {                                                                           \
    f16x8 a0[4][2], a1[4][2], vb0[2][2], vb1[2][2];                           \
    _Pragma("unroll") for (int i = 0; i < 4; ++i) {                           \
      a0[i][0] = *(const f16x8*)(lbase + (sb) + aoff + i * 2048 + so0);       \
      a0[i][1] = *(const f16x8*)(lbase + (sb) + aoff + i * 2048 + so1);       \
    }                                                                         \
    _Pragma("unroll") for (int j = 0; j < 2; ++j) {                           \
      vb0[j][0] = *(const f16x8*)(lbase + (sb) + boff + j * 2048 + so0);      \
      vb0[j][1] = *(const f16x8*)(lbase + (sb) + boff + j * 2048 + so1);      \
    }                                                                         \
    MFMA16(0, 0, a0, vb0);                                                    \
    _Pragma("unroll") for (int j = 0; j < 2; ++j) {                           \
      vb1[j][0] = *(const f16x8*)(lbase + (sb) + boff + (2+j) * 2048 + so0);  \
      vb1[j][1] = *(const f16x8*)(lbase + (sb) + boff + (2+j) * 2048 + so1);  \
    }                                                                         \
    MFMA16(0, 2, a0, vb1);                                                    \
    _Pragma("unroll") for (int i = 0; i < 4; ++i) {                           \
      a1[i][0] = *(const f16x8*)(lbase + (sb) + aoff + (4+i) * 2048 + so0);   \
      a1[i][1] = *(const f16x8*)(lbase + (sb) + aoff + (4+i) * 2048 + so1);   \
    }                                                                         \
    MFMA16(4, 2, a1, vb1);                                                    \
    MFMA16(4, 0, a1, vb0);                                                    \
  }

// ------------------- GEMM1: r20 K-loop, write-late A staging ---------------

__global__ __launch_bounds__(512, 2) void patch_gemm20(
    const float* __restrict__ pix,
    const _Float16* __restrict__ b1w,
    const float* __restrict__ bias1,
    const float* __restrict__ cosx, const float* __restrict__ sinx,
    const float* __restrict__ cosy, const float* __restrict__ siny,
    _Float16* __restrict__ peM)
{
  __shared__ _Float16 lds[2][2][256][64];   // 128 KiB (double-buffered)

  const int tid  = threadIdx.x;
  const int lane = tid & 63;
  const int wave = tid >> 6;
  const int wm = wave >> 2, wn = wave & 3;
  const int bm = blockIdx.x, bn = blockIdx.y;
  const int l15 = lane & 15;
  const int g   = lane >> 4;
  const int s7  = l15 & 7;

  const char* lbase = (const char*)lds;
  char*       lw    = (char*)lds;
  const unsigned aoff = (unsigned)(wm * 16384 + l15 * 128);
  const unsigned boff = (unsigned)(32768 + wn * 8192 + l15 * 128);
  const unsigned so0  = (unsigned)(((0 + g) ^ s7) * 16);
  const unsigned so1  = (unsigned)(((4 + g) ^ s7) * 16);

  const int bm256 = bm * 256, bn256 = bn * 256;
  const int srow = wave * 32 + (lane >> 3);        // B staging row base
  const int acol = lane & 15;                      // A f32 col16 within tile
  const int arw  = wave * 32 + (lane >> 4);        // A row base (per u: +4u)

  auto LOADA = [&](int s, float4 (&ar)[8]) {
    const bool full = (s < 9);
#pragma unroll
    for (int u = 0; u < 8; ++u) {
      const int row = arw + u * 4;
      const float* p = pix + (size_t)(bm256 + row) * 588 + s * 64 + acol * 4;
      if (full || acol < 3) ar[u] = *(const float4*)p;   // s=9: k<588 only
      else ar[u] = make_float4(0.f, 0.f, 0.f, 0.f);
    }
  };
  auto WRITEA = [&](int s, float4 (&ar)[8]) {
    char* slot = lw + ((size_t)((s) & 1) << 16);
    const int c   = acol >> 1;
    const int sub = acol & 1;
#pragma unroll
    for (int u = 0; u < 8; ++u) {
      const int row = arw + u * 4;
      f16x4 v;
      v[0] = (_Float16)ar[u].x; v[1] = (_Float16)ar[u].y;
      v[2] = (_Float16)ar[u].z; v[3] = (_Float16)ar[u].w;
      *(f16x4*)(slot + row * 128 + ((c ^ (row & 7)) * 16 + sub * 8)) = v;
    }
  };
  auto STAGE_B = [&](int s) {
    char* slot = lw + ((size_t)((s) & 1) << 16);
    const int c0 = s * 64;
#pragma unroll
    for (int u = 0; u < 4; ++u) {
      const int row  = srow + u * 8;
      const int gcol = (lane & 7) ^ (row & 7);
      gload_lds16(b1w + (size_t)(bn256 + row) * KP + c0 + gcol * 8,
                  slot + 32768 + (wave * 4 + u) * 1024);
    }
  };

  f32x4 acc[8][4] = {};
  float4 areg[8];

  LOADA(0, areg); STAGE_B(0);
  VM0; WRITEA(0, areg); LGKM0; BAR;

  for (int s = 0; s < 10; ++s) {
    const unsigned sb = (unsigned)((s & 1) << 16);
    const bool st = (s + 1 < 10);
    if (st) { LOADA(s + 1, areg); STAGE_B(s + 1); }   // issue early (top)
    __builtin_amdgcn_s_setprio(1);
    TILE_BODY(sb);                                    // full 64-MFMA cover
    __builtin_amdgcn_s_setprio(0);
    if (st) { VM0; WRITEA(s + 1, areg); }             // write late (end)
    LGKM0; BAR;
  }

  // ---- epilogue: per-wave LDS transpose -> vectorized gelu/rope/store -----
  BAR;   // all waves done reading K-loop LDS before overwrite
  float* sw = (float*)(lw) + wave * (32 * 65);
  const int md = (lane >> 4) * 4;
  const int rq = lane & 3;          // e-quarter
  const int lr = lane >> 2;         // row within 16-group
#pragma unroll
  for (int p = 0; p < 4; ++p) {
    // scatter my acc slice (rows mf=2p,2p+1) into the wave region
#pragma unroll
    for (int i = 0; i < 2; ++i)
#pragma unroll
      for (int r = 0; r < 4; ++r) {
        const int lrow = i * 16 + md + r;
#pragma unroll
        for (int nf = 0; nf < 4; ++nf)
          sw[lrow * 65 + nf * 16 + l15] = acc[2 * p + i][nf][r];
      }
    // gather: thread owns 16 consecutive e for 2 rows
#pragma unroll
    for (int rr = 0; rr < 2; ++rr) {
      const int lrow = rr * 16 + lr;
      const int m   = bm256 + wm * 128 + p * 32 + lrow;
      const int pid = m & 4095;
      const int yy = pid >> 6, xx = pid & 63;
      const int t  = (m >> 12) * 1024 + (yy >> 1) * 32 + (xx >> 1);
      const int pq = (yy & 1) * 2 + (xx & 1);
      const int e0 = bn256 + wn * 64 + rq * 16;
      const int h2 = (e0 >= 512) ? 1 : 0;
      const int idx0 = (h2 ? (e0 - 512) : e0) >> 1;      // mult of 8
      const int pos  = h2 ? yy : xx;
      const float* ct = (h2 ? cosy : cosx) + pos * 256 + idx0;
      const float* st = (h2 ? siny : sinx) + pos * 256 + idx0;
      const float4 c0 = *(const float4*)ct, c1 = *(const float4*)(ct + 4);
      const float4 s0 = *(const float4*)st, s1 = *(const float4*)(st + 4);
      const float4 b0 = *(const float4*)(bias1 + e0);
      const float4 b1 = *(const float4*)(bias1 + e0 + 4);
      const float4 b2 = *(const float4*)(bias1 + e0 + 8);
      const float4 b3 = *(const float4*)(bias1 + e0 + 12);
      const float bb[16] = {b0.x,b0.y,b0.z,b0.w, b1.x,b1.y,b1.z,b1.w,
                            b2.x,b2.y,b2.z,b2.w, b3.x,b3.y,b3.z,b3.w};
      float v[16];
#pragma unroll
      for (int j = 0; j < 16; ++j) {
        float x = sw[lrow * 65 + rq * 16 + j] + bb[j];
        v[j] = 0.5f * x * (1.0f + erff(x * 0.70710678118654752f));
      }
      const float cc[8] = {c0.x,c0.y,c0.z,c0.w, c1.x,c1.y,c1.z,c1.w};
      const float ss[8] = {s0.x,s0.y,s0.z,s0.w, s1.x,s1.y,s1.z,s1.w};
      _Float16 o[16];
#pragma unroll
      for (int k = 0; k < 8; ++k) {
        o[2*k]   = (_Float16)(v[2*k] * cc[k] - v[2*k+1] * ss[k]);
        o[2*k+1] = (_Float16)(v[2*k] * ss[k] + v[2*k+1] * cc[k]);
      }
      _Float16* dst = peM + (size_t)t * 4096 + pq * 1024 + e0;
      *(f16x8*)dst       = *(const f16x8*)&o[0];
      *(f16x8*)(dst + 8) = *(const f16x8*)&o[8];
    }
  }
}

// ------------------- GEMM2: r9 exact (127.5 us, MfmaUtil 50%) --------------

__global__ __launch_bounds__(512, 2) void dense_gemm9(
    const _Float16* __restrict__ aM,    // [8192][4096] merged pe
    const _Float16* __restrict__ bM,    // [2048][4096] permuted w2
    const float* __restrict__ bias2, float* __restrict__ out)
{
  __shared__ _Float16 lds[2][2][256][64];   // 128 KiB

  const int tid  = threadIdx.x;
  const int lane = tid & 63;
  const int wave = tid >> 6;
  const int wm = wave >> 2, wn = wave & 3;
  const int bm = blockIdx.x, bn = blockIdx.y;
  const int l15 = lane & 15;
  const int g   = lane >> 4;
  const int s7  = l15 & 7;

  const char* lbase = (const char*)lds;
  char*       lw    = (char*)lds;
  const unsigned aoff = (unsigned)(wm * 16384 + l15 * 128);
  const unsigned boff = (unsigned)(32768 + wn * 8192 + l15 * 128);
  const unsigned so0  = (unsigned)(((0 + g) ^ s7) * 16);
  const unsigned so1  = (unsigned)(((4 + g) ^ s7) * 16);

  const int bm256 = bm * 256, bn256 = bn * 256;
  const int srow = (wave * 4) * 8 + (lane >> 3);

  auto STAGE = [&](int s) {
    char* slot = lw + ((size_t)(s & 1) << 16);
    const int c0 = s * 64;
#pragma unroll
    for (int u = 0; u < 4; ++u) {
      const int row  = srow + u * 8;
      const int gcol = (lane & 7) ^ (row & 7);
      gload_lds16(aM + (size_t)(bm256 + row) * 4096 + c0 + gcol * 8,
                  slot + (wave * 4 + u) * 1024);
      gload_lds16(bM + (size_t)(bn256 + row) * 4096 + c0 + gcol * 8,
                  slot + 32768 + (wave * 4 + u) * 1024);
    }
  };

  f32x4 acc[8][4] = {};

  STAGE(0); VM0; BAR;
#pragma unroll 2
  for (int s = 0; s < 64; ++s) {
    if (s + 1 < 64) STAGE(s + 1);
    const unsigned sb = (unsigned)((s & 1) << 16);
    __builtin_amdgcn_s_setprio(1);
    TILE_BODY(sb);
    __builtin_amdgcn_s_setprio(0);
    LGKM0; VM0; BAR;
  }

  // epilogue
  const int md = (lane >> 4) * 4;
  const int r0 = bm256 + wm * 128;
  const int c0 = bn256 + wn * 64;
#pragma unroll
  for (int nf = 0; nf < 4; ++nf) {
    const int o = c0 + nf * 16 + l15;
    const float bs = bias2[o];
#pragma unroll
    for (int mf = 0; mf < 8; ++mf) {
      const int t_ = r0 + mf * 16 + md;
#pragma unroll
      for (int r = 0; r < 4; ++r)
        out[(size_t)(t_ + r) * 2048 + o] = acc[mf][nf][r] + bs;
    }
  }
}

// ----------------------------- launcher ------------------------------------

extern "C" void kernel_launch(void* const* d_in, const int* in_sizes, int n_in,
                              void* d_out, int out_size, void* d_ws, size_t ws_size,
                              hipStream_t stream) {
  const float* pix  = (const float*)d_in[0];
  const float* w1   = (const float*)d_in[2];
  const float* b1   = (const float*)d_in[3];
  const float* w2   = (const float*)d_in[4];
  const float* b2   = (const float*)d_in[5];
  const float* cosx = (const float*)d_in[6];
  const float* sinx = (const float*)d_in[7];
  const float* cosy = (const float*)d_in[8];
  const float* siny = (const float*)d_in[9];
  float* out = (float*)d_out;

  _Float16* ws = (_Float16*)d_ws;
  const size_t PE_N  = (size_t)8192 * 4096;
  const size_t B1_N  = (size_t)1024 * KP;
  _Float16* peM  = ws;
  _Float16* b1h  = peM + PE_N;
  _Float16* b2h  = b1h + B1_N;
  // total ws ~84 MB

  conv_w_kernel<<<dim3(2560 + 8192), dim3(256), 0, stream>>>(w1, w2, b1h, b2h);
  patch_gemm20<<<dim3(128, 4), dim3(512), 0, stream>>>(
      pix, b1h, b1, cosx, sinx, cosy, siny, peM);
  dense_gemm9<<<dim3(32, 8), dim3(512), 0, stream>>>(
      peM, b2h, b2, out);
}